// Round 6
// baseline (774.874 us; speedup 1.0000x reference)
//
#include <hip/hip_runtime.h>
#include <hip/hip_bf16.h>

typedef __attribute__((ext_vector_type(8))) __bf16 bx8;
typedef __attribute__((ext_vector_type(4))) float  fx4;

#define ROWS 8192   // B*S
#define HID  1024
#define MEMN 8192

// global_load_lds, 16B per lane; LDS dest = wave-uniform base + lane*16
#define GLDS(gp, lp) __builtin_amdgcn_global_load_lds( \
    (const __attribute__((address_space(1))) void*)(gp), \
    (__attribute__((address_space(3))) void*)(lp), 16, 0, 0)

#define MEMFENCE asm volatile("" ::: "memory")

// ---------------------------------------------------------------------------
// fp32 -> bf16 elementwise convert
// ---------------------------------------------------------------------------
__global__ __launch_bounds__(256)
void f32_to_bf16_vec(const float* __restrict__ in, __bf16* __restrict__ out)
{
    const size_t i = ((size_t)blockIdx.x * 256 + threadIdx.x) * 8;
    fx4 a = *(const fx4*)(in + i);
    fx4 b = *(const fx4*)(in + i + 4);
    bx8 u;
    u[0] = (__bf16)a[0]; u[1] = (__bf16)a[1]; u[2] = (__bf16)a[2]; u[3] = (__bf16)a[3];
    u[4] = (__bf16)b[0]; u[5] = (__bf16)b[1]; u[6] = (__bf16)b[2]; u[7] = (__bf16)b[3];
    *(bx8*)(out + i) = u;
}

// ---------------------------------------------------------------------------
// fp32 [R][C] -> bf16 [C][R] transpose (64x64 tiles via LDS)
// ---------------------------------------------------------------------------
__global__ __launch_bounds__(256)
void transpose_f32_to_bf16(const float* __restrict__ in, __bf16* __restrict__ out,
                           int R, int C)
{
    __shared__ float t[64][65];
    const int tid = threadIdx.x;
    const int r0 = blockIdx.y * 64;
    const int c0 = blockIdx.x * 64;
    const int lr = tid >> 4;
    const int lc = (tid & 15) * 4;
#pragma unroll
    for (int p = 0; p < 4; ++p) {
        const int rr = p * 16 + lr;
        const fx4 v = *(const fx4*)(in + (size_t)(r0 + rr) * C + c0 + lc);
        t[rr][lc + 0] = v[0]; t[rr][lc + 1] = v[1];
        t[rr][lc + 2] = v[2]; t[rr][lc + 3] = v[3];
    }
    __syncthreads();
    const int oc = tid >> 2;
    const int ob = (tid & 3) * 16;
    bx8 u0, u1;
#pragma unroll
    for (int j = 0; j < 8; ++j) {
        u0[j] = (__bf16)t[ob + j][oc];
        u1[j] = (__bf16)t[ob + 8 + j][oc];
    }
    *(bx8*)(out + (size_t)(c0 + oc) * R + r0 + ob)     = u0;
    *(bx8*)(out + (size_t)(c0 + oc) * R + r0 + ob + 8) = u1;
}

// ---------------------------------------------------------------------------
// In-place transpose of square bf16 matrix W [MEMN][MEMN], 64x64 tile pairs.
// ---------------------------------------------------------------------------
__global__ __launch_bounds__(256)
void transpose_inplace_bf16(__bf16* __restrict__ W)
{
    const int bi = blockIdx.y;
    const int bj = blockIdx.x;
    if (bi > bj) return;
    __shared__ __bf16 ta[64][72];
    __shared__ __bf16 tb[64][72];
    const int tid = threadIdx.x;
    const int lr = tid >> 3;
    const int lc = (tid & 7) * 8;
    const size_t N = MEMN;
    __bf16* At = W + (size_t)bi * 64 * N + (size_t)bj * 64;
    __bf16* Bt = W + (size_t)bj * 64 * N + (size_t)bi * 64;
#pragma unroll
    for (int p = 0; p < 2; ++p) {
        const int rr = p * 32 + lr;
        *(bx8*)(&ta[rr][lc]) = *(const bx8*)(At + (size_t)rr * N + lc);
        *(bx8*)(&tb[rr][lc]) = *(const bx8*)(Bt + (size_t)rr * N + lc);
    }
    __syncthreads();
    const int oc = tid >> 2;
    const int ob = (tid & 3) * 16;
    bx8 u0, u1, v0, v1;
#pragma unroll
    for (int j = 0; j < 8; ++j) {
        u0[j] = tb[ob + j][oc];  u1[j] = tb[ob + 8 + j][oc];
        v0[j] = ta[ob + j][oc];  v1[j] = ta[ob + 8 + j][oc];
    }
    *(bx8*)(At + (size_t)oc * N + ob)     = u0;
    *(bx8*)(At + (size_t)oc * N + ob + 8) = u1;
    *(bx8*)(Bt + (size_t)oc * N + ob)     = v0;
    *(bx8*)(Bt + (size_t)oc * N + ob + 8) = v1;
}

// ---------------------------------------------------------------------------
// Row softmax over 8192 bf16 logits, in place. One block/row, fp32 math.
// ---------------------------------------------------------------------------
__global__ __launch_bounds__(256)
void softmax_rows(__bf16* __restrict__ W)
{
    __bf16* row = W + (size_t)blockIdx.x * MEMN;
    const int tid = threadIdx.x;
    float v[32];
#pragma unroll
    for (int i = 0; i < 4; ++i) {
        bx8 u = *(const bx8*)(row + i * 2048 + tid * 8);
#pragma unroll
        for (int j = 0; j < 8; ++j) v[i * 8 + j] = (float)u[j];
    }
    float m = -1e30f;
#pragma unroll
    for (int i = 0; i < 32; ++i) m = fmaxf(m, v[i]);
#pragma unroll
    for (int off = 32; off >= 1; off >>= 1) m = fmaxf(m, __shfl_xor(m, off, 64));
    __shared__ float red[8];
    const int wave = tid >> 6, lane = tid & 63;
    if (lane == 0) red[wave] = m;
    __syncthreads();
    m = fmaxf(fmaxf(red[0], red[1]), fmaxf(red[2], red[3]));
    float s = 0.f;
#pragma unroll
    for (int i = 0; i < 32; ++i) { v[i] = __expf(v[i] - m); s += v[i]; }
#pragma unroll
    for (int off = 32; off >= 1; off >>= 1) s += __shfl_xor(s, off, 64);
    if (lane == 0) red[4 + wave] = s;
    __syncthreads();
    s = (red[4] + red[5]) + (red[6] + red[7]);
    const float inv = 1.0f / s;
#pragma unroll
    for (int i = 0; i < 4; ++i) {
        bx8 u;
#pragma unroll
        for (int j = 0; j < 8; ++j) u[j] = (__bf16)(v[i * 8 + j] * inv);
        *(bx8*)(row + i * 2048 + tid * 8) = u;
    }
}

// ---------------------------------------------------------------------------
// gemm8: round-3 NT GEMM, ring-4 ledger unchanged, but with the read/MFMA
// DUAL-WINDOW split: {stage(t+2) + ds_read -> barrier -> setprio MFMA ->
// counted vmcnt -> barrier}. Barriers added only (same data hazards ledger:
// at end of tile t, in-flight = stage(t+2)'s L loads -> vmcnt(L) guarantees
// stage(t+1) landed before any wave reads slot t+1).
// ---------------------------------------------------------------------------
template <int BM, int BN, int MODE>
__global__ __launch_bounds__(512)
void gemm8(const __bf16* __restrict__ A, const __bf16* __restrict__ B,
           const float* __restrict__ bias, const float* __restrict__ add,
           void* __restrict__ out, int N, int K, int nBN)
{
    constexpr int ASZ = BM * 64;
    constexpr int BSZ = BN * 64;
    constexpr int RA  = BM / 128;
    constexpr int RB  = BN / 128;
    constexpr int L   = RA + RB;
    constexpr int RWM = BM / 2, RWN = BN / 4;
    constexpr int FM  = RWM / 16, FN = RWN / 16;

    __shared__ __align__(16) char smem[4 * (ASZ + BSZ)];

    const int tid = threadIdx.x;
    const int wid = tid >> 6;
    const int ln  = tid & 63;
    const int fl  = ln & 15;
    const int fh  = ln >> 4;
    const int wr  = wid >> 2;
    const int wc  = wid & 3;

    const int nwg = gridDim.x;
    const int bid = blockIdx.x;
    const int wg  = (bid & 7) * (nwg >> 3) + (bid >> 3);
    const int tm  = (wg / nBN) * BM;
    const int tn  = (wg % nBN) * BN;

    const int NT = K / 32;

    const __bf16* Ag[RA];
    const __bf16* Bg[RB];
#pragma unroll
    for (int R = 0; R < RA; ++R) {
        const int p = R * 512 + tid;
        Ag[R] = A + (size_t)(tm + (p >> 2)) * K + ((p & 3) ^ ((p >> 3) & 3)) * 8;
    }
#pragma unroll
    for (int R = 0; R < RB; ++R) {
        const int p = R * 512 + tid;
        Bg[R] = B + (size_t)(tn + (p >> 2)) * K + ((p & 3) ^ ((p >> 3) & 3)) * 8;
    }

    auto stage = [&](int t) {
        const int s = t & 3;
        const size_t ko = (size_t)t * 32;
        char* Ad = smem + s * ASZ + wid * 1024;
        char* Bd = smem + 4 * ASZ + s * BSZ + wid * 1024;
#pragma unroll
        for (int R = 0; R < RA; ++R) GLDS(Ag[R] + ko, Ad + R * 8192);
#pragma unroll
        for (int R = 0; R < RB; ++R) GLDS(Bg[R] + ko, Bd + R * 8192);
    };

    fx4 acc[FM][FN] = {};

    stage(0);
    stage(1);
    asm volatile("s_waitcnt vmcnt(%0)" :: "i"(L) : "memory");
    __builtin_amdgcn_s_barrier();
    MEMFENCE;

    for (int t = 0; t < NT; ++t) {
        // ---- R window: stage next-next tile + read this tile's fragments ----
        if (t + 2 < NT) stage(t + 2);

        const char* Ab = smem + (t & 3) * ASZ;
        const char* Bb = smem + 4 * ASZ + (t & 3) * BSZ;
        bx8 fa[FM], fb[FN];
#pragma unroll
        for (int mi = 0; mi < FM; ++mi) {
            const int r = wr * RWM + mi * 16 + fl;
            fa[mi] = *(const bx8*)(Ab + r * 64 + ((fh ^ ((r >> 1) & 3)) << 4));
        }
#pragma unroll
        for (int ni = 0; ni < FN; ++ni) {
            const int c = wc * RWN + ni * 16 + fl;
            fb[ni] = *(const bx8*)(Bb + c * 64 + ((fh ^ ((c >> 1) & 3)) << 4));
        }
        MEMFENCE;
        __builtin_amdgcn_s_barrier();
        MEMFENCE;

        // ---- M window: MFMA cluster, then counted wait for next tile ----
        __builtin_amdgcn_s_setprio(1);
#pragma unroll
        for (int mi = 0; mi < FM; ++mi)
#pragma unroll
            for (int ni = 0; ni < FN; ++ni)
                acc[mi][ni] = __builtin_amdgcn_mfma_f32_16x16x32_bf16(
                    fa[mi], fb[ni], acc[mi][ni], 0, 0, 0);
        __builtin_amdgcn_s_setprio(0);
        if (t + 2 < NT)      asm volatile("s_waitcnt vmcnt(%0)" :: "i"(L) : "memory");
        else if (t + 1 < NT) asm volatile("s_waitcnt vmcnt(0)" ::: "memory");
        MEMFENCE;
        __builtin_amdgcn_s_barrier();
        MEMFENCE;
    }

#pragma unroll
    for (int mi = 0; mi < FM; ++mi) {
#pragma unroll
        for (int ni = 0; ni < FN; ++ni) {
            const int gr0 = tm + wr * RWM + mi * 16 + fh * 4;
            const int gc  = tn + wc * RWN + ni * 16 + fl;
            fx4 c = acc[mi][ni];
            if constexpr (MODE == 0) {
                __bf16* O = (__bf16*)out;
                const float bv = bias[gc];
#pragma unroll
                for (int j = 0; j < 4; ++j)
                    O[(size_t)(gr0 + j) * N + gc] = (__bf16)(c[j] + bv);
            } else if constexpr (MODE == 1) {
                float* O = (float*)out;
#pragma unroll
                for (int j = 0; j < 4; ++j)
                    O[(size_t)(gr0 + j) * N + gc] = c[j];
            } else {
                float* O = (float*)out;
#pragma unroll
                for (int j = 0; j < 4; ++j) {
                    const size_t idx = (size_t)(gr0 + j) * N + gc;
                    O[idx] = c[j] + add[idx];
                }
            }
        }
    }
}

// ---------------------------------------------------------------------------
// gemm_dp2: 256x256 NT GEMM for the logits, m201-style dual-window phases.
// BK=32, 512 thr = 8 waves (2Mx4N), wave tile 128x64, acc[8][4].
// LDS: ring-3 x (A 16KB + B 16KB) = 96 KiB. Round-3 ledger: stage(t+2)
// issued during tile t (slot (t+2)%3 disjoint from t, t+1; its old contents
// were consumed in tile t-1, before the barrier we've since crossed).
// One vmcnt(4) per K-tile at end of M2 (stage(t+2)'s 4 loads in flight,
// stage(t+1) guaranteed landed); vmcnt(0) only at the tail.
// Per K-tile: 2 phase-pairs, each {stage-half || ds_read -> barrier ->
// setprio 16 MFMA setprio -> barrier}  (read/MFMA window alternation).
// Swizzle identical to round 3 (PMC: 0 bank conflicts).
// ---------------------------------------------------------------------------
__global__ __launch_bounds__(512, 2)
void gemm_dp2(const __bf16* __restrict__ A, const __bf16* __restrict__ B,
              const float* __restrict__ bias, __bf16* __restrict__ out,
              int N, int K, int nBN)
{
    constexpr int ASZ = 256 * 64;      // 16 KiB per slot (256 rows x 64 B)
    __shared__ __align__(16) char smem[6 * ASZ];   // 3 A slots + 3 B slots
    char* const As = smem;
    char* const Bs = smem + 3 * ASZ;

    const int tid = threadIdx.x;
    const int wid = tid >> 6;
    const int ln  = tid & 63;
    const int fl  = ln & 15;
    const int fh  = ln >> 4;
    const int wr  = wid >> 2;          // 0..1 -> rows wr*128
    const int wc  = wid & 3;           // 0..3 -> cols wc*64

    const int nwg = gridDim.x;
    const int bid = blockIdx.x;
    const int wg  = (bid & 7) * (nwg >> 3) + (bid >> 3);
    const int tm  = (wg / nBN) * 256;
    const int tn  = (wg % nBN) * 256;
    const int NT  = K / 32;

    // staging sources, round-3 swizzle: granule p covers row p>>2,
    // src k-granule (p&3)^((p>>3)&3)
    const __bf16* Ag[2];
    const __bf16* Bg[2];
#pragma unroll
    for (int R = 0; R < 2; ++R) {
        const int p = R * 512 + tid;
        Ag[R] = A + (size_t)(tm + (p >> 2)) * K + ((p & 3) ^ ((p >> 3) & 3)) * 8;
        Bg[R] = B + (size_t)(tn + (p >> 2)) * K + ((p & 3) ^ ((p >> 3) & 3)) * 8;
    }

    auto stA = [&](int t) {
        const int s = t % 3;
        const size_t ko = (size_t)t * 32;
        GLDS(Ag[0] + ko, As + s * ASZ + wid * 1024);
        GLDS(Ag[1] + ko, As + s * ASZ + 8192 + wid * 1024);
    };
    auto stB = [&](int t) {
        const int s = t % 3;
        const size_t ko = (size_t)t * 32;
        GLDS(Bg[0] + ko, Bs + s * ASZ + wid * 1024);
        GLDS(Bg[1] + ko, Bs + s * ASZ + 8192 + wid * 1024);
    };

    fx4 acc[8][4] = {};

    stA(0); stB(0); stA(1); stB(1);
    asm volatile("s_waitcnt vmcnt(4)" ::: "memory");
    __builtin_amdgcn_s_barrier();
    MEMFENCE;

    for (int t = 0; t < NT; ++t) {
        const char* Ab = As + (t % 3) * ASZ;
        const char* Bb = Bs + (t % 3) * ASZ;
        const bool pf = (t + 2 < NT);
        bx8 fa[4], fb[4];

        // ---- R1: stage A(t+2) + read fb, fa(mh=0) ----
        if (pf) stA(t + 2);
#pragma unroll
        for (int ni = 0; ni < 4; ++ni) {
            const int c = wc * 64 + ni * 16 + fl;
            fb[ni] = *(const bx8*)(Bb + c * 64 + ((fh ^ ((c >> 1) & 3)) << 4));
        }
#pragma unroll
        for (int mi = 0; mi < 4; ++mi) {
            const int r = wr * 128 + mi * 16 + fl;
            fa[mi] = *(const bx8*)(Ab + r * 64 + ((fh ^ ((r >> 1) & 3)) << 4));
        }
        MEMFENCE;
        __builtin_amdgcn_s_barrier();
        MEMFENCE;

        // ---- M1: MFMA mh=0 ----
        __builtin_amdgcn_s_setprio(1);
#pragma unroll
        for (int mi = 0; mi < 4; ++mi)
#pragma unroll
            for (int ni = 0; ni < 4; ++ni)
                acc[mi][ni] = __builtin_amdgcn_mfma_f32_16x16x32_bf16(
                    fa[mi], fb[ni], acc[mi][ni], 0, 0, 0);
        __builtin_amdgcn_s_setprio(0);
        MEMFENCE;
        __builtin_amdgcn_s_barrier();
        MEMFENCE;

        // ---- R2: stage B(t+2) + read fa(mh=1) ----
        if (pf) stB(t + 2);
#pragma unroll
        for (int mi = 0; mi < 4; ++mi) {
            const int r = wr * 128 + 64 + mi * 16 + fl;
            fa[mi] = *(const bx8*)(Ab + r * 64 + ((fh ^ ((r >> 1) & 3)) << 4));
        }
        MEMFENCE;
        __builtin_amdgcn_s_barrier();
        MEMFENCE;

        // ---- M2: MFMA mh=1, then counted wait for next tile ----
        __builtin_amdgcn_s_setprio(1);
#pragma unroll
        for (int mi = 0; mi < 4; ++mi)
#pragma unroll
            for (int ni = 0; ni < 4; ++ni)
                acc[4 + mi][ni] = __builtin_amdgcn_mfma_f32_16x16x32_bf16(
                    fa[mi], fb[ni], acc[4 + mi][ni], 0, 0, 0);
        __builtin_amdgcn_s_setprio(0);
        if (pf)              asm volatile("s_waitcnt vmcnt(4)" ::: "memory");
        else if (t + 1 < NT) asm volatile("s_waitcnt vmcnt(0)" ::: "memory");
        MEMFENCE;
        __builtin_amdgcn_s_barrier();
        MEMFENCE;
    }

    // epilogue: bf16 out + bias
#pragma unroll
    for (int mh = 0; mh < 2; ++mh)
#pragma unroll
        for (int mi = 0; mi < 4; ++mi)
#pragma unroll
            for (int ni = 0; ni < 4; ++ni) {
                const int gr0 = tm + wr * 128 + mh * 64 + mi * 16 + fh * 4;
                const int gc  = tn + wc * 64 + ni * 16 + fl;
                const float bv = bias[gc];
                fx4 c = acc[mh * 4 + mi][ni];
#pragma unroll
                for (int j = 0; j < 4; ++j)
                    out[(size_t)(gr0 + j) * N + gc] = (__bf16)(c[j] + bv);
            }
}

// ---------------------------------------------------------------------------
// Orchestration. ws layout (176 MiB):
//   xb    [8192,1024] bf16  @ 0
//   slot1 [8192,1024] bf16  @ 16 MiB  (rwb then wwb)
//   slot2 [1024,8192] bf16  @ 32 MiB  (memT then xT)
//   W     [8192,8192] bf16  @ 48 MiB
// ---------------------------------------------------------------------------
extern "C" void kernel_launch(void* const* d_in, const int* in_sizes, int n_in,
                              void* d_out, int out_size, void* d_ws, size_t ws_size,
                              hipStream_t stream)
{
    const float* x       = (const float*)d_in[0];
    const float* memory  = (const float*)d_in[1];
    const float* read_w  = (const float*)d_in[2];
    const float* read_b  = (const float*)d_in[3];
    const float* write_w = (const float*)d_in[4];
    const float* write_b = (const float*)d_in[5];

    float* out_read = (float*)d_out;
    float* out_mem  = (float*)d_out + (size_t)MEMN * HID;

    char* p = (char*)d_ws;
    const size_t MiB = 1024 * 1024;
    __bf16* xb    = (__bf16*)(p + 0 * MiB);
    __bf16* slot1 = (__bf16*)(p + 16 * MiB);
    __bf16* slot2 = (__bf16*)(p + 32 * MiB);
    __bf16* W     = (__bf16*)(p + 48 * MiB);

    // ---- read path ---------------------------------------------------------
    f32_to_bf16_vec<<<4096, 256, 0, stream>>>(x, xb);
    f32_to_bf16_vec<<<4096, 256, 0, stream>>>(read_w, slot1);
    transpose_f32_to_bf16<<<dim3(HID / 64, ROWS / 64), 256, 0, stream>>>(memory, slot2, ROWS, HID);
    gemm_dp2<<<(ROWS / 256) * (MEMN / 256), 512, 0, stream>>>(
        xb, slot1, read_b, W, MEMN, HID, MEMN / 256);
    softmax_rows<<<ROWS, 256, 0, stream>>>(W);
    gemm8<128, 256, 1><<<(ROWS / 128) * (HID / 256), 512, 0, stream>>>(
        W, slot2, nullptr, nullptr, out_read, HID, MEMN, HID / 256);

    // ---- write path --------------------------------------------------------
    f32_to_bf16_vec<<<4096, 256, 0, stream>>>(write_w, slot1);
    transpose_f32_to_bf16<<<dim3(HID / 64, ROWS / 64), 256, 0, stream>>>(x, slot2, ROWS, HID);
    gemm_dp2<<<(ROWS / 256) * (MEMN / 256), 512, 0, stream>>>(
        xb, slot1, write_b, W, MEMN, HID, MEMN / 256);
    softmax_rows<<<ROWS, 256, 0, stream>>>(W);
    transpose_inplace_bf16<<<dim3(MEMN / 64, MEMN / 64), 256, 0, stream>>>(W);
    gemm8<128, 256, 2><<<(MEMN / 128) * (HID / 256), 512, 0, stream>>>(
        W, slot2, nullptr, memory, out_mem, HID, ROWS, HID / 256);
}

// Round 7
// 766.088 us; speedup vs baseline: 1.0115x; 1.0115x over previous
//
#include <hip/hip_runtime.h>
#include <hip/hip_bf16.h>

typedef __attribute__((ext_vector_type(8))) __bf16 bx8;
typedef __attribute__((ext_vector_type(4))) float  fx4;

#define ROWS 8192   // B*S
#define HID  1024
#define MEMN 8192

// global_load_lds, 16B per lane; LDS dest = wave-uniform base + lane*16
#define GLDS(gp, lp) __builtin_amdgcn_global_load_lds( \
    (const __attribute__((address_space(1))) void*)(gp), \
    (__attribute__((address_space(3))) void*)(lp), 16, 0, 0)

#define MEMFENCE asm volatile("" ::: "memory")

// ---------------------------------------------------------------------------
// fp32 -> bf16 elementwise convert
// ---------------------------------------------------------------------------
__global__ __launch_bounds__(256)
void f32_to_bf16_vec(const float* __restrict__ in, __bf16* __restrict__ out)
{
    const size_t i = ((size_t)blockIdx.x * 256 + threadIdx.x) * 8;
    fx4 a = *(const fx4*)(in + i);
    fx4 b = *(const fx4*)(in + i + 4);
    bx8 u;
    u[0] = (__bf16)a[0]; u[1] = (__bf16)a[1]; u[2] = (__bf16)a[2]; u[3] = (__bf16)a[3];
    u[4] = (__bf16)b[0]; u[5] = (__bf16)b[1]; u[6] = (__bf16)b[2]; u[7] = (__bf16)b[3];
    *(bx8*)(out + i) = u;
}

// ---------------------------------------------------------------------------
// fp32 [R][C] -> bf16 [C][R] transpose (64x64 tiles via LDS)
// ---------------------------------------------------------------------------
__global__ __launch_bounds__(256)
void transpose_f32_to_bf16(const float* __restrict__ in, __bf16* __restrict__ out,
                           int R, int C)
{
    __shared__ float t[64][65];
    const int tid = threadIdx.x;
    const int r0 = blockIdx.y * 64;
    const int c0 = blockIdx.x * 64;
    const int lr = tid >> 4;
    const int lc = (tid & 15) * 4;
#pragma unroll
    for (int p = 0; p < 4; ++p) {
        const int rr = p * 16 + lr;
        const fx4 v = *(const fx4*)(in + (size_t)(r0 + rr) * C + c0 + lc);
        t[rr][lc + 0] = v[0]; t[rr][lc + 1] = v[1];
        t[rr][lc + 2] = v[2]; t[rr][lc + 3] = v[3];
    }
    __syncthreads();
    const int oc = tid >> 2;
    const int ob = (tid & 3) * 16;
    bx8 u0, u1;
#pragma unroll
    for (int j = 0; j < 8; ++j) {
        u0[j] = (__bf16)t[ob + j][oc];
        u1[j] = (__bf16)t[ob + 8 + j][oc];
    }
    *(bx8*)(out + (size_t)(c0 + oc) * R + r0 + ob)     = u0;
    *(bx8*)(out + (size_t)(c0 + oc) * R + r0 + ob + 8) = u1;
}

// ---------------------------------------------------------------------------
// Row softmax over 8192 bf16 logits, in place (read path). fp32 math.
// ---------------------------------------------------------------------------
__global__ __launch_bounds__(256)
void softmax_rows(__bf16* __restrict__ W)
{
    __bf16* row = W + (size_t)blockIdx.x * MEMN;
    const int tid = threadIdx.x;
    float v[32];
#pragma unroll
    for (int i = 0; i < 4; ++i) {
        bx8 u = *(const bx8*)(row + i * 2048 + tid * 8);
#pragma unroll
        for (int j = 0; j < 8; ++j) v[i * 8 + j] = (float)u[j];
    }
    float m = -1e30f;
#pragma unroll
    for (int i = 0; i < 32; ++i) m = fmaxf(m, v[i]);
#pragma unroll
    for (int off = 32; off >= 1; off >>= 1) m = fmaxf(m, __shfl_xor(m, off, 64));
    __shared__ float red[8];
    const int wave = tid >> 6, lane = tid & 63;
    if (lane == 0) red[wave] = m;
    __syncthreads();
    m = fmaxf(fmaxf(red[0], red[1]), fmaxf(red[2], red[3]));
    float s = 0.f;
#pragma unroll
    for (int i = 0; i < 32; ++i) { v[i] = __expf(v[i] - m); s += v[i]; }
#pragma unroll
    for (int off = 32; off >= 1; off >>= 1) s += __shfl_xor(s, off, 64);
    if (lane == 0) red[4 + wave] = s;
    __syncthreads();
    s = (red[4] + red[5]) + (red[6] + red[7]);
    const float inv = 1.0f / s;
#pragma unroll
    for (int i = 0; i < 4; ++i) {
        bx8 u;
#pragma unroll
        for (int j = 0; j < 8; ++j) u[j] = (__bf16)(v[i * 8 + j] * inv);
        *(bx8*)(row + i * 2048 + tid * 8) = u;
    }
}

// ---------------------------------------------------------------------------
// Row softmax STATS only (write path): per-row (max, 1/sum) -> stats[row].
// Same reduction structure as softmax_rows, no write-back of W.
// ---------------------------------------------------------------------------
__global__ __launch_bounds__(256)
void softmax_stats(const __bf16* __restrict__ W, float2* __restrict__ stats)
{
    const __bf16* row = W + (size_t)blockIdx.x * MEMN;
    const int tid = threadIdx.x;
    float v[32];
#pragma unroll
    for (int i = 0; i < 4; ++i) {
        bx8 u = *(const bx8*)(row + i * 2048 + tid * 8);
#pragma unroll
        for (int j = 0; j < 8; ++j) v[i * 8 + j] = (float)u[j];
    }
    float m = -1e30f;
#pragma unroll
    for (int i = 0; i < 32; ++i) m = fmaxf(m, v[i]);
#pragma unroll
    for (int off = 32; off >= 1; off >>= 1) m = fmaxf(m, __shfl_xor(m, off, 64));
    __shared__ float red[8];
    const int wave = tid >> 6, lane = tid & 63;
    if (lane == 0) red[wave] = m;
    __syncthreads();
    m = fmaxf(fmaxf(red[0], red[1]), fmaxf(red[2], red[3]));
    float s = 0.f;
#pragma unroll
    for (int i = 0; i < 32; ++i) s += __expf(v[i] - m);
#pragma unroll
    for (int off = 32; off >= 1; off >>= 1) s += __shfl_xor(s, off, 64);
    if (lane == 0) red[4 + wave] = s;
    __syncthreads();
    if (tid == 0) {
        s = (red[4] + red[5]) + (red[6] + red[7]);
        stats[blockIdx.x] = make_float2(m, 1.0f / s);
    }
}

// ---------------------------------------------------------------------------
// In-place scale+transpose of W [MEMN][MEMN]: W <- softmax(W)^T, where the
// softmax scaling uses precomputed per-SOURCE-row stats (m, inv).
// 64x64 tile pairs, same swap scheme as the verified transpose_inplace;
// exp-scale applied at load time (before LDS).
// ---------------------------------------------------------------------------
__global__ __launch_bounds__(256)
void scale_transpose_inplace(__bf16* __restrict__ W,
                             const float2* __restrict__ stats)
{
    const int bi = blockIdx.y;
    const int bj = blockIdx.x;
    if (bi > bj) return;
    __shared__ __bf16 ta[64][72];
    __shared__ __bf16 tb[64][72];
    const int tid = threadIdx.x;
    const int lr = tid >> 3;          // 0..31
    const int lc = (tid & 7) * 8;     // 0..56
    const size_t N = MEMN;
    __bf16* At = W + (size_t)bi * 64 * N + (size_t)bj * 64;
    __bf16* Bt = W + (size_t)bj * 64 * N + (size_t)bi * 64;
#pragma unroll
    for (int p = 0; p < 2; ++p) {
        const int rr = p * 32 + lr;
        const float2 sa = stats[bi * 64 + rr];
        const float2 sb = stats[bj * 64 + rr];
        bx8 va = *(const bx8*)(At + (size_t)rr * N + lc);
        bx8 vb = *(const bx8*)(Bt + (size_t)rr * N + lc);
#pragma unroll
        for (int j = 0; j < 8; ++j) {
            ta[rr][lc + j] = (__bf16)(__expf((float)va[j] - sa.x) * sa.y);
            tb[rr][lc + j] = (__bf16)(__expf((float)vb[j] - sb.x) * sb.y);
        }
    }
    __syncthreads();
    const int oc = tid >> 2;
    const int ob = (tid & 3) * 16;
    bx8 u0, u1, v0, v1;
#pragma unroll
    for (int j = 0; j < 8; ++j) {
        u0[j] = tb[ob + j][oc];  u1[j] = tb[ob + 8 + j][oc];
        v0[j] = ta[ob + j][oc];  v1[j] = ta[ob + 8 + j][oc];
    }
    *(bx8*)(At + (size_t)oc * N + ob)     = u0;
    *(bx8*)(At + (size_t)oc * N + ob + 8) = u1;
    *(bx8*)(Bt + (size_t)oc * N + ob)     = v0;
    *(bx8*)(Bt + (size_t)oc * N + ob + 8) = v1;
}

// ---------------------------------------------------------------------------
// gemm8: round-3 verified NT GEMM (exact). Used for the two logits GEMMs
// at <256,256,0>. Ring-4 LDS, one vmcnt + one barrier per K-tile.
// ---------------------------------------------------------------------------
template <int BM, int BN, int MODE>
__global__ __launch_bounds__(512)
void gemm8(const __bf16* __restrict__ A, const __bf16* __restrict__ B,
           const float* __restrict__ bias, const float* __restrict__ add,
           void* __restrict__ out, int N, int K, int nBN)
{
    constexpr int ASZ = BM * 64;
    constexpr int BSZ = BN * 64;
    constexpr int RA  = BM / 128;
    constexpr int RB  = BN / 128;
    constexpr int L   = RA + RB;
    constexpr int RWM = BM / 2, RWN = BN / 4;
    constexpr int FM  = RWM / 16, FN = RWN / 16;

    __shared__ __align__(16) char smem[4 * (ASZ + BSZ)];

    const int tid = threadIdx.x;
    const int wid = tid >> 6;
    const int ln  = tid & 63;
    const int fl  = ln & 15;
    const int fh  = ln >> 4;
    const int wr  = wid >> 2;
    const int wc  = wid & 3;

    const int nwg = gridDim.x;
    const int bid = blockIdx.x;
    const int wg  = (bid & 7) * (nwg >> 3) + (bid >> 3);
    const int tm  = (wg / nBN) * BM;
    const int tn  = (wg % nBN) * BN;

    const int NT = K / 32;

    const __bf16* Ag[RA];
    const __bf16* Bg[RB];
#pragma unroll
    for (int R = 0; R < RA; ++R) {
        const int p = R * 512 + tid;
        Ag[R] = A + (size_t)(tm + (p >> 2)) * K + ((p & 3) ^ ((p >> 3) & 3)) * 8;
    }
#pragma unroll
    for (int R = 0; R < RB; ++R) {
        const int p = R * 512 + tid;
        Bg[R] = B + (size_t)(tn + (p >> 2)) * K + ((p & 3) ^ ((p >> 3) & 3)) * 8;
    }

    auto stage = [&](int t) {
        const int s = t & 3;
        const size_t ko = (size_t)t * 32;
        char* Ad = smem + s * ASZ + wid * 1024;
        char* Bd = smem + 4 * ASZ + s * BSZ + wid * 1024;
#pragma unroll
        for (int R = 0; R < RA; ++R) GLDS(Ag[R] + ko, Ad + R * 8192);
#pragma unroll
        for (int R = 0; R < RB; ++R) GLDS(Bg[R] + ko, Bd + R * 8192);
    };

    fx4 acc[FM][FN] = {};

    stage(0);
    if (NT > 1) stage(1);

    for (int t = 0; t < NT; ++t) {
        if (t == NT - 1) {
            asm volatile("s_waitcnt vmcnt(0)" ::: "memory");
        } else if constexpr (L == 4) {
            asm volatile("s_waitcnt vmcnt(4)" ::: "memory");
        } else {
            asm volatile("s_waitcnt vmcnt(3)" ::: "memory");
        }
        __builtin_amdgcn_s_barrier();
        MEMFENCE;
        if (t + 2 < NT) stage(t + 2);

        const char* Ab = smem + (t & 3) * ASZ;
        const char* Bb = smem + 4 * ASZ + (t & 3) * BSZ;
        bx8 fa[FM], fb[FN];
#pragma unroll
        for (int mi = 0; mi < FM; ++mi) {
            const int r = wr * RWM + mi * 16 + fl;
            fa[mi] = *(const bx8*)(Ab + r * 64 + ((fh ^ ((r >> 1) & 3)) << 4));
        }
#pragma unroll
        for (int ni = 0; ni < FN; ++ni) {
            const int c = wc * RWN + ni * 16 + fl;
            fb[ni] = *(const bx8*)(Bb + c * 64 + ((fh ^ ((c >> 1) & 3)) << 4));
        }
        __builtin_amdgcn_s_setprio(1);
#pragma unroll
        for (int mi = 0; mi < FM; ++mi)
#pragma unroll
            for (int ni = 0; ni < FN; ++ni)
                acc[mi][ni] = __builtin_amdgcn_mfma_f32_16x16x32_bf16(
                    fa[mi], fb[ni], acc[mi][ni], 0, 0, 0);
        __builtin_amdgcn_s_setprio(0);
    }

#pragma unroll
    for (int mi = 0; mi < FM; ++mi) {
#pragma unroll
        for (int ni = 0; ni < FN; ++ni) {
            const int gr0 = tm + wr * RWM + mi * 16 + fh * 4;
            const int gc  = tn + wc * RWN + ni * 16 + fl;
            fx4 c = acc[mi][ni];
            if constexpr (MODE == 0) {
                __bf16* O = (__bf16*)out;
                const float bv = bias[gc];
#pragma unroll
                for (int j = 0; j < 4; ++j)
                    O[(size_t)(gr0 + j) * N + gc] = (__bf16)(c[j] + bv);
            } else if constexpr (MODE == 1) {
                float* O = (float*)out;
#pragma unroll
                for (int j = 0; j < 4; ++j)
                    O[(size_t)(gr0 + j) * N + gc] = c[j];
            } else {
                float* O = (float*)out;
#pragma unroll
                for (int j = 0; j < 4; ++j) {
                    const size_t idx = (size_t)(gr0 + j) * N + gc;
                    O[idx] = c[j] + add[idx];
                }
            }
        }
    }
}

// ---------------------------------------------------------------------------
// gemm4w: 128x128 NT GEMM, 256 thr = 4 waves (2Mx2N), wave tile 64x64,
// acc[4][4]. Ring-3 LDS = 48 KiB -> up to 3 blocks/CU; barrier domains of
// co-resident blocks are independent, so one block's MFMA fills another's
// barrier/vmcnt drain (m97/m114 mechanism). Same ledger as round 3:
// stage(t+2) after the tile-top barrier (slot (t+2)%3 disjoint from t,t+1;
// its old data was consumed before the barrier we just crossed); counted
// vmcnt(4) at tile top (stage(t+1)'s 4 loads stay in flight, in-order drain
// guarantees stage(t) landed); vmcnt(0) only at the last tile. Swizzle
// identical to round 3 (PMC-verified 0 bank conflicts).
// MODE 1: f32 out; MODE 2: f32 out + add[idx].
// ---------------------------------------------------------------------------
template <int MODE>
__global__ __launch_bounds__(256, 3)
void gemm4w(const __bf16* __restrict__ A, const __bf16* __restrict__ B,
            const float* __restrict__ add, float* __restrict__ out,
            int N, int K, int nBN)
{
    constexpr int SLT = 128 * 64;                  // 8 KiB per matrix slot
    __shared__ __align__(16) char smem[6 * SLT];   // 3 A slots + 3 B slots
    char* const As = smem;
    char* const Bs = smem + 3 * SLT;

    const int tid = threadIdx.x;
    const int wid = tid >> 6;          // 0..3
    const int ln  = tid & 63;
    const int fl  = ln & 15;
    const int fh  = ln >> 4;
    const int wr  = wid >> 1;          // 0..1
    const int wc  = wid & 1;           // 0..1

    const int nwg = gridDim.x;
    const int bid = blockIdx.x;
    const int wg  = (bid & 7) * (nwg >> 3) + (bid >> 3);
    const int tm  = (wg / nBN) * 128;
    const int tn  = (wg % nBN) * 128;
    const int NT  = K / 32;

    // pre-swizzled sources: granule p -> row p>>2, src k-granule (p&3)^((p>>3)&3)
    const __bf16* Ag[2];
    const __bf16* Bg[2];
#pragma unroll
    for (int R = 0; R < 2; ++R) {
        const int p = R * 256 + tid;
        Ag[R] = A + (size_t)(tm + (p >> 2)) * K + ((p & 3) ^ ((p >> 3) & 3)) * 8;
        Bg[R] = B + (size_t)(tn + (p >> 2)) * K + ((p & 3) ^ ((p >> 3) & 3)) * 8;
    }

    auto stage = [&](int t) {
        const int s = t % 3;
        const size_t ko = (size_t)t * 32;
        GLDS(Ag[0] + ko, As + s * SLT + wid * 1024);
        GLDS(Ag[1] + ko, As + s * SLT + 4096 + wid * 1024);
        GLDS(Bg[0] + ko, Bs + s * SLT + wid * 1024);
        GLDS(Bg[1] + ko, Bs + s * SLT + 4096 + wid * 1024);
    };

    fx4 acc[4][4] = {};

    stage(0);
    stage(1);

    for (int t = 0; t < NT; ++t) {
        if (t == NT - 1) asm volatile("s_waitcnt vmcnt(0)" ::: "memory");
        else             asm volatile("s_waitcnt vmcnt(4)" ::: "memory");
        __builtin_amdgcn_s_barrier();
        MEMFENCE;
        if (t + 2 < NT) stage(t + 2);

        const char* Ab = As + (t % 3) * SLT;
        const char* Bb = Bs + (t % 3) * SLT;
        bx8 fa[4], fb[4];
#pragma unroll
        for (int mi = 0; mi < 4; ++mi) {
            const int r = wr * 64 + mi * 16 + fl;
            fa[mi] = *(const bx8*)(Ab + r * 64 + ((fh ^ ((r >> 1) & 3)) << 4));
        }
#pragma unroll
        for (int ni = 0; ni < 4; ++ni) {
            const int c = wc * 64 + ni * 16 + fl;
            fb[ni] = *(const bx8*)(Bb + c * 64 + ((fh ^ ((c >> 1) & 3)) << 4));
        }
        __builtin_amdgcn_s_setprio(1);
#pragma unroll
        for (int mi = 0; mi < 4; ++mi)
#pragma unroll
            for (int ni = 0; ni < 4; ++ni)
                acc[mi][ni] = __builtin_amdgcn_mfma_f32_16x16x32_bf16(
                    fa[mi], fb[ni], acc[mi][ni], 0, 0, 0);
        __builtin_amdgcn_s_setprio(0);
    }

#pragma unroll
    for (int mi = 0; mi < 4; ++mi) {
#pragma unroll
        for (int ni = 0; ni < 4; ++ni) {
            const int gr0 = tm + wr * 64 + mi * 16 + fh * 4;
            const int gc  = tn + wc * 64 + ni * 16 + fl;
            fx4 c = acc[mi][ni];
            if constexpr (MODE == 1) {
#pragma unroll
                for (int j = 0; j < 4; ++j)
                    out[(size_t)(gr0 + j) * N + gc] = c[j];
            } else {
#pragma unroll
                for (int j = 0; j < 4; ++j) {
                    const size_t idx = (size_t)(gr0 + j) * N + gc;
                    out[idx] = c[j] + add[idx];
                }
            }
        }
    }
}

// ---------------------------------------------------------------------------
// Orchestration. ws layout (176 MiB):
//   xb    [8192,1024] bf16  @ 0
//   slot1 [8192,1024] bf16  @ 16 MiB  (rwb, then wwb, then stats f32x2[8192])
//   slot2 [1024,8192] bf16  @ 32 MiB  (memT then xT)
//   W     [8192,8192] bf16  @ 48 MiB
// ---------------------------------------------------------------------------
extern "C" void kernel_launch(void* const* d_in, const int* in_sizes, int n_in,
                              void* d_out, int out_size, void* d_ws, size_t ws_size,
                              hipStream_t stream)
{
    const float* x       = (const float*)d_in[0];
    const float* memory  = (const float*)d_in[1];
    const float* read_w  = (const float*)d_in[2];
    const float* read_b  = (const float*)d_in[3];
    const float* write_w = (const float*)d_in[4];
    const float* write_b = (const float*)d_in[5];

    float* out_read = (float*)d_out;
    float* out_mem  = (float*)d_out + (size_t)MEMN * HID;

    char* p = (char*)d_ws;
    const size_t MiB = 1024 * 1024;
    __bf16* xb    = (__bf16*)(p + 0 * MiB);
    __bf16* slot1 = (__bf16*)(p + 16 * MiB);
    __bf16* slot2 = (__bf16*)(p + 32 * MiB);
    __bf16* W     = (__bf16*)(p + 48 * MiB);
    float2* stats = (float2*)(p + 16 * MiB);   // reuses slot1 after wwb is dead

    // ---- read path ---------------------------------------------------------
    f32_to_bf16_vec<<<4096, 256, 0, stream>>>(x, xb);
    f32_to_bf16_vec<<<4096, 256, 0, stream>>>(read_w, slot1);
    transpose_f32_to_bf16<<<dim3(HID / 64, ROWS / 64), 256, 0, stream>>>(memory, slot2, ROWS, HID);
    gemm8<256, 256, 0><<<(ROWS / 256) * (MEMN / 256), 512, 0, stream>>>(
        xb, slot1, read_b, nullptr, W, MEMN, HID, MEMN / 256);
    softmax_rows<<<ROWS, 256, 0, stream>>>(W);
    gemm4w<1><<<(ROWS / 128) * (HID / 128), 256, 0, stream>>>(
        W, slot2, nullptr, out_read, HID, MEMN, HID / 128);

    // ---- write path --------------------------------------------------------
    f32_to_bf16_vec<<<4096, 256, 0, stream>>>(write_w, slot1);
    transpose_f32_to_bf16<<<dim3(HID / 64, ROWS / 64), 256, 0, stream>>>(x, slot2, ROWS, HID);
    gemm8<256, 256, 0><<<(ROWS / 256) * (MEMN / 256), 512, 0, stream>>>(
        xb, slot1, write_b, nullptr, W, MEMN, HID, MEMN / 256);
    softmax_stats<<<ROWS, 256, 0, stream>>>(W, stats);
    scale_transpose_inplace<<<dim3(MEMN / 64, MEMN / 64), 256, 0, stream>>>(W, stats);
    gemm4w<2><<<(MEMN / 128) * (HID / 128), 256, 0, stream>>>(
        W, slot2, memory, out_mem, HID, ROWS, HID / 128);
}